// Round 13
// baseline (127.359 us; speedup 1.0000x reference)
//
#include <hip/hip_runtime.h>
#include <hip/hip_bf16.h>

// Problem constants
#define BB 64
#define NN 500
#define CC 256
#define HH 64
#define WW 64
#define HWSZ 4096
#define NPTS 32000
#define NPAD 512

typedef __attribute__((ext_vector_type(4))) short s4v;
typedef __attribute__((ext_vector_type(8))) short s8v;
typedef __attribute__((ext_vector_type(4))) float f4v;
typedef __attribute__((ext_vector_type(4))) int i4v;

// split f32 -> hi bf16 + lo bf16 (RNE), x ~= hi + lo with rel err ~2^-17
__device__ __forceinline__ void bfsplit(float f, unsigned short& h, unsigned short& l) {
    unsigned u = __builtin_bit_cast(unsigned, f);
    unsigned hr = (u + 0x7FFFu + ((u >> 16) & 1u)) >> 16;
    h = (unsigned short)hr;
    float hf = __builtin_bit_cast(float, hr << 16);
    float r = f - hf;
    unsigned v = __builtin_bit_cast(unsigned, r);
    unsigned lr = (v + 0x7FFFu + ((v >> 16) & 1u)) >> 16;
    l = (unsigned short)lr;
}

// ---------------------------------------------------------------------------
// K1: gather + prep + weight-pack (r11-identical: gather blocks first,
// pack tail). blk < GATHER_BLKS: gather. Else: weight-frag pack + fcwT.
// ---------------------------------------------------------------------------
#define CHPB 2
#define GATHER_BLKS 8192
#define W0F_N 32768   // 8 Mt * 8 s * 512
#define W1F_N 24576   // 4 Mt * 12 s * 512
#define W2F_N 5120    // 1 Mt * 10 s * 512
#define PACK_N (W0F_N + W1F_N + W2F_N)
#define FCT_N 590000
#define PACKALL_N (PACK_N + FCT_N)
#define PACK_BLKS ((PACKALL_N + 511) / 512)

__global__ __launch_bounds__(512) void k_gp(const float* __restrict__ sfeat,
                                            const float* __restrict__ pts,
                                            const float* __restrict__ w0,
                                            const float* __restrict__ w1,
                                            const float* __restrict__ w2,
                                            const float* __restrict__ fcw,
                                            unsigned short* __restrict__ featI,
                                            unsigned short* __restrict__ w0fh,
                                            unsigned short* __restrict__ w0fl,
                                            unsigned short* __restrict__ w1fh,
                                            unsigned short* __restrict__ w1fl,
                                            unsigned short* __restrict__ w2fh,
                                            unsigned short* __restrict__ w2fl,
                                            float* __restrict__ fcwT) {
    __shared__ float im[CHPB * HWSZ];   // 32 KB
    const int blk = blockIdx.x;
    const int tid = threadIdx.x;

    if (blk >= GATHER_BLKS) {
        // ---- pack path ----
        int i = (blk - GATHER_BLKS) * 512 + tid;
        if (i < W0F_N) {
            int j = i & 7, ll = (i >> 3) & 63, s = (i >> 9) & 7, m = i >> 12;
            int row = m * 16 + (ll & 15), k = s * 32 + (ll >> 4) * 8 + j;
            unsigned short h, l; bfsplit(w0[row * 256 + k], h, l);
            w0fh[i] = h; w0fl[i] = l;
        } else if (i < W0F_N + W1F_N) {
            int d = i - W0F_N;
            int j = d & 7, ll = (d >> 3) & 63, rest = d >> 9;
            int s = rest % 12, m = rest / 12;
            int row = m * 16 + (ll & 15), k = s * 32 + (ll >> 4) * 8 + j;
            unsigned short h, l; bfsplit(w1[row * 384 + k], h, l);
            w1fh[d] = h; w1fl[d] = l;
        } else if (i < PACK_N) {
            int d = i - (W0F_N + W1F_N);
            int j = d & 7, ll = (d >> 3) & 63, s = d >> 9;
            int row = ll & 15, k = s * 32 + (ll >> 4) * 8 + j;
            float v = (row < 5) ? w2[row * 320 + k] : 0.f;
            unsigned short h, l; bfsplit(v, h, l);
            w2fh[d] = h; w2fl[d] = l;
        } else if (i < PACKALL_N) {
            int d = i - PACK_N;
            int k = d / 236, o = d - k * 236;
            fcwT[d] = fcw[o * 2500 + k];
        }
        return;
    }

    // ---- gather path ----
    const int b  = blk >> 7;            // 128 channel-groups per batch
    const int cg = blk & 127;
    const int c0 = cg * CHPB;

    const float4* src4 = (const float4*)(sfeat + ((size_t)b * CC + c0) * HWSZ);
#pragma unroll
    for (int it = 0; it < CHPB * (HWSZ / 4) / 512; it++) {   // 4 iters
        int j = it * 512 + tid;
        __builtin_amdgcn_global_load_lds(
            (const __attribute__((address_space(1))) void*)(src4 + j),
            (__attribute__((address_space(3))) void*)((float4*)im + j),
            16, 0, 0);
    }

    int4 id = make_int4(0, 0, 0, 0);
    float4 wt = make_float4(0.f, 0.f, 0.f, 0.f);
    const int n = tid;
    if (n < NN) {
        float x = (pts[((size_t)b * NN + n) * 2 + 0] + 1.f) * 0.5f * (float)(WW - 1);
        float y = (pts[((size_t)b * NN + n) * 2 + 1] + 1.f) * 0.5f * (float)(HH - 1);
        float x0f = floorf(x), y0f = floorf(y);
        float x1f = x0f + 1.f, y1f = y0f + 1.f;
        float wx1 = x - x0f, wx0 = 1.f - wx1;
        float wy1 = y - y0f, wy0 = 1.f - wy1;
        float mx0 = (x0f >= 0.f && x0f <= (float)(WW - 1)) ? 1.f : 0.f;
        float mx1 = (x1f >= 0.f && x1f <= (float)(WW - 1)) ? 1.f : 0.f;
        float my0 = (y0f >= 0.f && y0f <= (float)(HH - 1)) ? 1.f : 0.f;
        float my1 = (y1f >= 0.f && y1f <= (float)(HH - 1)) ? 1.f : 0.f;
        int x0 = (int)fminf(fmaxf(x0f, 0.f), (float)(WW - 1));
        int x1 = (int)fminf(fmaxf(x1f, 0.f), (float)(WW - 1));
        int y0 = (int)fminf(fmaxf(y0f, 0.f), (float)(HH - 1));
        int y1 = (int)fminf(fmaxf(y1f, 0.f), (float)(HH - 1));
        id = make_int4(y0 * WW + x0, y0 * WW + x1, y1 * WW + x0, y1 * WW + x1);
        wt = make_float4(wx0 * wy0 * mx0 * my0, wx1 * wy0 * mx1 * my0,
                         wx0 * wy1 * mx0 * my1, wx1 * wy1 * mx1 * my1);
    }
    __syncthreads();

    if (n < NN) {
        unsigned short h[CHPB], lo[CHPB];
#pragma unroll
        for (int j = 0; j < CHPB; j++) {
            const float* L = im + j * HWSZ;
            float r = wt.x * L[id.x] + wt.y * L[id.y] + wt.z * L[id.z] + wt.w * L[id.w];
            bfsplit(r, h[j], lo[j]);
        }
        s4v v; v[0] = (short)h[0]; v[1] = (short)h[1];
               v[2] = (short)lo[0]; v[3] = (short)lo[1];
        *(s4v*)&featI[(((size_t)b * 128 + cg) * NPAD + n) * 4] = v;
    }
}

// ---------------------------------------------------------------------------
// K2: split-bf16 MFMA fused MLP (byte-identical to r9/r11).
// ---------------------------------------------------------------------------
#define K1_S 136
#define K2_S 72

__device__ __forceinline__ s8v mkfrag(const unsigned short* p) {
    return *(const s8v*)p;
}

__global__ __launch_bounds__(512, 4) void k_mlp(const unsigned short* __restrict__ featI,
                                                const unsigned short* __restrict__ w0fh,
                                                const unsigned short* __restrict__ w0fl,
                                                const unsigned short* __restrict__ w1fh,
                                                const unsigned short* __restrict__ w1fl,
                                                const unsigned short* __restrict__ w2fh,
                                                const unsigned short* __restrict__ w2fl,
                                                const float* __restrict__ b0,
                                                const float* __restrict__ b1,
                                                const float* __restrict__ b2,
                                                float* __restrict__ y2f) {
    __shared__ unsigned short c1H[32 * K1_S];
    __shared__ unsigned short c1L[32 * K1_S];
    __shared__ unsigned short c2H[32 * K2_S];
    __shared__ unsigned short c2L[32 * K2_S];   // total 26,624 B

    const int b   = blockIdx.y;
    const int n0  = blockIdx.x * 32;
    const int tid = threadIdx.x;
    const int w   = tid >> 6, l = tid & 63;
    const int nt  = w & 1, mh = w >> 1;
    const int lo16 = l & 15, hi = l >> 4;
    const int c = nt * 16 + lo16;          // point column 0..31

    // ---- B-fragments: 32 x 8B loads; dword t of bhs[s] = low dword of load t
    s8v bhs[8], bls[8];
    const unsigned short* fbase = featI + (((size_t)b * 128) * NPAD + (n0 + c)) * 4;
#pragma unroll
    for (int s = 0; s < 8; s++) {
        const int kgb = s * 16 + hi * 4;
        i4v hx, lx;
#pragma unroll
        for (int t = 0; t < 4; t++) {
            int2 v = *(const int2*)(fbase + (size_t)(kgb + t) * (NPAD * 4));
            hx[t] = v.x; lx[t] = v.y;
        }
        bhs[s] = __builtin_bit_cast(s8v, hx);
        bls[s] = __builtin_bit_cast(s8v, lx);
    }

    // ---- layer 0: 128 outs (8 Mt), K=256; wave does Mt = 2mh, 2mh+1 ----
    f4v acc0 = {0.f, 0.f, 0.f, 0.f}, acc1 = {0.f, 0.f, 0.f, 0.f};
#pragma unroll
    for (int s = 0; s < 8; s++) {
        const s8v a0h = mkfrag(w0fh + ((size_t)((mh * 2) * 8 + s) * 64 + l) * 8);
        const s8v a0l = mkfrag(w0fl + ((size_t)((mh * 2) * 8 + s) * 64 + l) * 8);
        const s8v a1h = mkfrag(w0fh + ((size_t)((mh * 2 + 1) * 8 + s) * 64 + l) * 8);
        const s8v a1l = mkfrag(w0fl + ((size_t)((mh * 2 + 1) * 8 + s) * 64 + l) * 8);
        acc0 = __builtin_amdgcn_mfma_f32_16x16x32_bf16(a0h, bhs[s], acc0, 0, 0, 0);
        acc0 = __builtin_amdgcn_mfma_f32_16x16x32_bf16(a0h, bls[s], acc0, 0, 0, 0);
        acc0 = __builtin_amdgcn_mfma_f32_16x16x32_bf16(a0l, bhs[s], acc0, 0, 0, 0);
        acc1 = __builtin_amdgcn_mfma_f32_16x16x32_bf16(a1h, bhs[s], acc1, 0, 0, 0);
        acc1 = __builtin_amdgcn_mfma_f32_16x16x32_bf16(a1h, bls[s], acc1, 0, 0, 0);
        acc1 = __builtin_amdgcn_mfma_f32_16x16x32_bf16(a1l, bhs[s], acc1, 0, 0, 0);
    }
#pragma unroll
    for (int m = 0; m < 2; m++) {
#pragma unroll
        for (int r = 0; r < 4; r++) {
            int ch = (mh * 2 + m) * 16 + hi * 4 + r;
            float v = (m ? acc1[r] : acc0[r]) + b0[ch];
            v = v > 0.f ? v : 0.01f * v;
            unsigned short hh, ll2; bfsplit(v, hh, ll2);
            c1H[c * K1_S + ch] = hh;
            c1L[c * K1_S + ch] = ll2;
        }
    }
    __syncthreads();

    // ---- layer 1: 64 outs (4 Mt), K=128(c1)+256(feat); wave: Mt = mh ----
    f4v accA = {0.f, 0.f, 0.f, 0.f};
#pragma unroll
    for (int s = 0; s < 4; s++) {
        const s8v bh = *(const s8v*)&c1H[c * K1_S + s * 32 + hi * 8];
        const s8v bl = *(const s8v*)&c1L[c * K1_S + s * 32 + hi * 8];
        const s8v ah = mkfrag(w1fh + ((size_t)(mh * 12 + s) * 64 + l) * 8);
        const s8v al = mkfrag(w1fl + ((size_t)(mh * 12 + s) * 64 + l) * 8);
        accA = __builtin_amdgcn_mfma_f32_16x16x32_bf16(ah, bh, accA, 0, 0, 0);
        accA = __builtin_amdgcn_mfma_f32_16x16x32_bf16(ah, bl, accA, 0, 0, 0);
        accA = __builtin_amdgcn_mfma_f32_16x16x32_bf16(al, bh, accA, 0, 0, 0);
    }
#pragma unroll
    for (int s = 4; s < 12; s++) {
        const s8v ah = mkfrag(w1fh + ((size_t)(mh * 12 + s) * 64 + l) * 8);
        const s8v al = mkfrag(w1fl + ((size_t)(mh * 12 + s) * 64 + l) * 8);
        accA = __builtin_amdgcn_mfma_f32_16x16x32_bf16(ah, bhs[s - 4], accA, 0, 0, 0);
        accA = __builtin_amdgcn_mfma_f32_16x16x32_bf16(ah, bls[s - 4], accA, 0, 0, 0);
        accA = __builtin_amdgcn_mfma_f32_16x16x32_bf16(al, bhs[s - 4], accA, 0, 0, 0);
    }
#pragma unroll
    for (int r = 0; r < 4; r++) {
        int ch = mh * 16 + hi * 4 + r;
        float v = accA[r] + b1[ch];
        v = v > 0.f ? v : 0.01f * v;
        unsigned short hh, ll2; bfsplit(v, hh, ll2);
        c2H[c * K2_S + ch] = hh;
        c2L[c * K2_S + ch] = ll2;
    }
    __syncthreads();

    // ---- layer 2: 5 outs (1 Mt), K=64(c2)+256(feat); waves mh==0 ----
    if (mh == 0) {
        f4v acc2 = {0.f, 0.f, 0.f, 0.f};
#pragma unroll
        for (int s = 0; s < 2; s++) {
            const s8v bh = *(const s8v*)&c2H[c * K2_S + s * 32 + hi * 8];
            const s8v bl = *(const s8v*)&c2L[c * K2_S + s * 32 + hi * 8];
            const s8v ah = mkfrag(w2fh + ((size_t)s * 64 + l) * 8);
            const s8v al = mkfrag(w2fl + ((size_t)s * 64 + l) * 8);
            acc2 = __builtin_amdgcn_mfma_f32_16x16x32_bf16(ah, bh, acc2, 0, 0, 0);
            acc2 = __builtin_amdgcn_mfma_f32_16x16x32_bf16(ah, bl, acc2, 0, 0, 0);
            acc2 = __builtin_amdgcn_mfma_f32_16x16x32_bf16(al, bh, acc2, 0, 0, 0);
        }
#pragma unroll
        for (int s = 2; s < 10; s++) {
            const s8v ah = mkfrag(w2fh + ((size_t)s * 64 + l) * 8);
            const s8v al = mkfrag(w2fl + ((size_t)s * 64 + l) * 8);
            acc2 = __builtin_amdgcn_mfma_f32_16x16x32_bf16(ah, bhs[s - 2], acc2, 0, 0, 0);
            acc2 = __builtin_amdgcn_mfma_f32_16x16x32_bf16(ah, bls[s - 2], acc2, 0, 0, 0);
            acc2 = __builtin_amdgcn_mfma_f32_16x16x32_bf16(al, bhs[s - 2], acc2, 0, 0, 0);
        }
#pragma unroll
        for (int r = 0; r < 4; r++) {
            int ch = hi * 4 + r;
            if (ch < 5) {
                float v = acc2[r] + b2[ch];
                v = fmaxf(v, 0.f);
                int n = n0 + c;
                if (n < NN) y2f[(size_t)b * 2500 + ch * NN + n] = v;
            }
        }
    }
}

// ---------------------------------------------------------------------------
// K3: FC two-stage (r11-identical).
// ---------------------------------------------------------------------------
__global__ __launch_bounds__(256) void k_fc1(const float* __restrict__ y2f,
                                             const float* __restrict__ fcwT,
                                             float* __restrict__ part) {
    __shared__ float ys[313];
    const int b  = blockIdx.x & 63;
    const int kc = blockIdx.x >> 6;
    const int start = kc * 312 + (kc < 4 ? kc : 4);
    const int len   = (kc < 4) ? 313 : 312;
    const float* yb = y2f + (size_t)b * 2500 + start;
    for (int j = threadIdx.x; j < len; j += 256) ys[j] = yb[j];
    __syncthreads();
    const int o = threadIdx.x;
    if (o < 236) {
        float acc = 0.f;
        const float* wp = fcwT + (size_t)start * 236 + o;
#pragma unroll 8
        for (int k = 0; k < len; k++) acc = fmaf(wp[(size_t)k * 236], ys[k], acc);
        part[((size_t)kc * 64 + b) * 236 + o] = acc;
    }
}

__global__ __launch_bounds__(256) void k_fc2(const float* __restrict__ part,
                                             const float* __restrict__ fcb,
                                             float* __restrict__ out) {
    const int b = blockIdx.x;
    const int o = threadIdx.x;
    if (o < 236) {
        float acc = fcb[o];
#pragma unroll
        for (int kc = 0; kc < 8; kc++) acc += part[((size_t)kc * 64 + b) * 236 + o];
        out[b * 236 + o] = acc;
    }
}

// ---------------------------------------------------------------------------
extern "C" void kernel_launch(void* const* d_in, const int* in_sizes, int n_in,
                              void* d_out, int out_size, void* d_ws, size_t ws_size,
                              hipStream_t stream) {
    const float* p   = (const float*)d_in[0];
    const float* sf  = (const float*)d_in[1];
    const float* w0  = (const float*)d_in[2];
    const float* b0  = (const float*)d_in[3];
    const float* w1  = (const float*)d_in[4];
    const float* b1  = (const float*)d_in[5];
    const float* w2  = (const float*)d_in[6];
    const float* b2  = (const float*)d_in[7];
    const float* fcw = (const float*)d_in[8];
    const float* fcb = (const float*)d_in[9];
    float* out = (float*)d_out;

    char* ws = (char*)d_ws;
    // ws layout (bytes):
    unsigned short* featI = (unsigned short*)(ws);             // [64][128][512][4] 33,554,432
    float*          y2f   = (float*)(ws + 33554432);           //     640,000
    float*          fcwT  = (float*)(ws + 34194432);           //   2,360,000
    float*          part  = (float*)(ws + 36554432);           //     483,328
    unsigned short* w0fh  = (unsigned short*)(ws + 37037760);  //      65,536
    unsigned short* w0fl  = (unsigned short*)(ws + 37103296);  //      65,536
    unsigned short* w1fh  = (unsigned short*)(ws + 37168832);  //      49,152
    unsigned short* w1fl  = (unsigned short*)(ws + 37217984);  //      49,152
    unsigned short* w2fh  = (unsigned short*)(ws + 37267136);  //      10,240
    unsigned short* w2fl  = (unsigned short*)(ws + 37277376);  //      10,240
                                                               // end: 37,287,616

    k_gp<<<GATHER_BLKS + PACK_BLKS, 512, 0, stream>>>(sf, p, w0, w1, w2, fcw,
                                                      featI, w0fh, w0fl, w1fh, w1fl,
                                                      w2fh, w2fl, fcwT);
    // MEASUREMENT ROUND: k_mlp launched twice (idempotent). dur - 101.8 = t_mlp.
    k_mlp<<<dim3(16, BB), 512, 0, stream>>>(featI, w0fh, w0fl, w1fh, w1fl,
                                            w2fh, w2fl, b0, b1, b2, y2f);
    k_mlp<<<dim3(16, BB), 512, 0, stream>>>(featI, w0fh, w0fl, w1fh, w1fl,
                                            w2fh, w2fl, b0, b1, b2, y2f);
    k_fc1<<<512, 256, 0, stream>>>(y2f, fcwT, part);
    k_fc2<<<BB, 256, 0, stream>>>(part, fcb, out);
}

// Round 14
// 101.986 us; speedup vs baseline: 1.2488x; 1.2488x over previous
//
#include <hip/hip_runtime.h>
#include <hip/hip_bf16.h>

// Problem constants
#define BB 64
#define NN 500
#define CC 256
#define HH 64
#define WW 64
#define HWSZ 4096
#define NPTS 32000
#define NPAD 512

typedef __attribute__((ext_vector_type(4))) short s4v;
typedef __attribute__((ext_vector_type(8))) short s8v;
typedef __attribute__((ext_vector_type(4))) float f4v;
typedef __attribute__((ext_vector_type(4))) int i4v;

// split f32 -> hi bf16 + lo bf16 (RNE), x ~= hi + lo with rel err ~2^-17
__device__ __forceinline__ void bfsplit(float f, unsigned short& h, unsigned short& l) {
    unsigned u = __builtin_bit_cast(unsigned, f);
    unsigned hr = (u + 0x7FFFu + ((u >> 16) & 1u)) >> 16;
    h = (unsigned short)hr;
    float hf = __builtin_bit_cast(float, hr << 16);
    float r = f - hf;
    unsigned v = __builtin_bit_cast(unsigned, r);
    unsigned lr = (v + 0x7FFFu + ((v >> 16) & 1u)) >> 16;
    l = (unsigned short)lr;
}

// ---------------------------------------------------------------------------
// K1: gather (pipelined) + weight-pack.
//  blk < 1024: persistent gather block = (batch, 16-channel chunk), 512 thr,
//    2x16KB LDS double buffer. Per iteration t (one channel):
//      issue DMA for ch t+1 into buf[(t+1)&1]  (2x global_load_lds 16B/thr)
//      s_waitcnt vmcnt(2)   <- ch t landed; ch t+1 stays in flight (T4)
//      s_barrier; gather ch t from buf[t&1]; s_barrier
//    featI store every odd t (channel pair interleaved split-bf16, 8B/lane).
//    Prep (bilinear idx/wt) computed once per block.
//  blk >= 1024: weight fragment pack + fcwT (r11-identical).
// ---------------------------------------------------------------------------
#define GATHER_BLKS 1024
#define NCHB 16
#define W0F_N 32768   // 8 Mt * 8 s * 512
#define W1F_N 24576   // 4 Mt * 12 s * 512
#define W2F_N 5120    // 1 Mt * 10 s * 512
#define PACK_N (W0F_N + W1F_N + W2F_N)
#define FCT_N 590000
#define PACKALL_N (PACK_N + FCT_N)
#define PACK_BLKS ((PACKALL_N + 511) / 512)

__global__ __launch_bounds__(512) void k_gp(const float* __restrict__ sfeat,
                                            const float* __restrict__ pts,
                                            const float* __restrict__ w0,
                                            const float* __restrict__ w1,
                                            const float* __restrict__ w2,
                                            const float* __restrict__ fcw,
                                            unsigned short* __restrict__ featI,
                                            unsigned short* __restrict__ w0fh,
                                            unsigned short* __restrict__ w0fl,
                                            unsigned short* __restrict__ w1fh,
                                            unsigned short* __restrict__ w1fl,
                                            unsigned short* __restrict__ w2fh,
                                            unsigned short* __restrict__ w2fl,
                                            float* __restrict__ fcwT) {
    __shared__ float im[2][HWSZ];   // 32 KB
    const int blk = blockIdx.x;
    const int tid = threadIdx.x;

    if (blk >= GATHER_BLKS) {
        // ---- pack path (r11-identical) ----
        int i = (blk - GATHER_BLKS) * 512 + tid;
        if (i < W0F_N) {
            int j = i & 7, ll = (i >> 3) & 63, s = (i >> 9) & 7, m = i >> 12;
            int row = m * 16 + (ll & 15), k = s * 32 + (ll >> 4) * 8 + j;
            unsigned short h, l; bfsplit(w0[row * 256 + k], h, l);
            w0fh[i] = h; w0fl[i] = l;
        } else if (i < W0F_N + W1F_N) {
            int d = i - W0F_N;
            int j = d & 7, ll = (d >> 3) & 63, rest = d >> 9;
            int s = rest % 12, m = rest / 12;
            int row = m * 16 + (ll & 15), k = s * 32 + (ll >> 4) * 8 + j;
            unsigned short h, l; bfsplit(w1[row * 384 + k], h, l);
            w1fh[d] = h; w1fl[d] = l;
        } else if (i < PACK_N) {
            int d = i - (W0F_N + W1F_N);
            int j = d & 7, ll = (d >> 3) & 63, s = d >> 9;
            int row = ll & 15, k = s * 32 + (ll >> 4) * 8 + j;
            float v = (row < 5) ? w2[row * 320 + k] : 0.f;
            unsigned short h, l; bfsplit(v, h, l);
            w2fh[d] = h; w2fl[d] = l;
        } else if (i < PACKALL_N) {
            int d = i - PACK_N;
            int k = d / 236, o = d - k * 236;
            fcwT[d] = fcw[o * 2500 + k];
        }
        return;
    }

    // ---- gather path ----
    const int b     = blk >> 4;
    const int chunk = blk & 15;
    const int ch0   = chunk * NCHB;
    const int n     = tid;

    // per-point bilinear prep, once per block
    int4 id = make_int4(0, 0, 0, 0);
    float4 wt = make_float4(0.f, 0.f, 0.f, 0.f);
    if (n < NN) {
        float x = (pts[((size_t)b * NN + n) * 2 + 0] + 1.f) * 0.5f * (float)(WW - 1);
        float y = (pts[((size_t)b * NN + n) * 2 + 1] + 1.f) * 0.5f * (float)(HH - 1);
        float x0f = floorf(x), y0f = floorf(y);
        float x1f = x0f + 1.f, y1f = y0f + 1.f;
        float wx1 = x - x0f, wx0 = 1.f - wx1;
        float wy1 = y - y0f, wy0 = 1.f - wy1;
        float mx0 = (x0f >= 0.f && x0f <= (float)(WW - 1)) ? 1.f : 0.f;
        float mx1 = (x1f >= 0.f && x1f <= (float)(WW - 1)) ? 1.f : 0.f;
        float my0 = (y0f >= 0.f && y0f <= (float)(HH - 1)) ? 1.f : 0.f;
        float my1 = (y1f >= 0.f && y1f <= (float)(HH - 1)) ? 1.f : 0.f;
        int x0 = (int)fminf(fmaxf(x0f, 0.f), (float)(WW - 1));
        int x1 = (int)fminf(fmaxf(x1f, 0.f), (float)(WW - 1));
        int y0 = (int)fminf(fmaxf(y0f, 0.f), (float)(HH - 1));
        int y1 = (int)fminf(fmaxf(y1f, 0.f), (float)(HH - 1));
        id = make_int4(y0 * WW + x0, y0 * WW + x1, y1 * WW + x0, y1 * WW + x1);
        wt = make_float4(wx0 * wy0 * mx0 * my0, wx1 * wy0 * mx1 * my0,
                         wx0 * wy1 * mx0 * my1, wx1 * wy1 * mx1 * my1);
    }

    const float4* src = (const float4*)(sfeat + ((size_t)b * CC + ch0) * HWSZ);

    // prologue: issue DMA for ch 0 into buf 0
#pragma unroll
    for (int it = 0; it < 2; it++) {
        int j = it * 512 + tid;
        __builtin_amdgcn_global_load_lds(
            (const __attribute__((address_space(1))) void*)(src + j),
            (__attribute__((address_space(3))) void*)((float4*)im[0] + j),
            16, 0, 0);
    }

    unsigned short hprev = 0, lprev = 0;
    for (int t = 0; t < NCHB; t++) {
        if (t + 1 < NCHB) {
            const float4* s2 = src + (size_t)(t + 1) * (HWSZ / 4);
            float4* dst = (float4*)im[(t + 1) & 1];
#pragma unroll
            for (int it = 0; it < 2; it++) {
                int j = it * 512 + tid;
                __builtin_amdgcn_global_load_lds(
                    (const __attribute__((address_space(1))) void*)(s2 + j),
                    (__attribute__((address_space(3))) void*)(dst + j),
                    16, 0, 0);
            }
            asm volatile("s_waitcnt vmcnt(2)" ::: "memory");  // ch t landed
        } else {
            asm volatile("s_waitcnt vmcnt(0)" ::: "memory");
        }
        asm volatile("s_barrier" ::: "memory");   // all waves: ch t visible

        if (n < NN) {
            const float* L = im[t & 1];
            float r = wt.x * L[id.x] + wt.y * L[id.y] + wt.z * L[id.z] + wt.w * L[id.w];
            unsigned short h, l; bfsplit(r, h, l);
            if (t & 1) {
                s4v v; v[0] = (short)hprev; v[1] = (short)h;
                       v[2] = (short)lprev; v[3] = (short)l;
                size_t cg = (size_t)(chunk * 8 + (t >> 1));
                *(s4v*)&featI[(((size_t)b * 128 + cg) * NPAD + n) * 4] = v;
            } else {
                hprev = h; lprev = l;
            }
        }
        if (t + 1 < NCHB)
            asm volatile("s_barrier" ::: "memory");  // reads done before overwrite
    }
}

// ---------------------------------------------------------------------------
// K2: split-bf16 MFMA fused MLP (byte-identical to r9/r11).
// ---------------------------------------------------------------------------
#define K1_S 136
#define K2_S 72

__device__ __forceinline__ s8v mkfrag(const unsigned short* p) {
    return *(const s8v*)p;
}

__global__ __launch_bounds__(512, 4) void k_mlp(const unsigned short* __restrict__ featI,
                                                const unsigned short* __restrict__ w0fh,
                                                const unsigned short* __restrict__ w0fl,
                                                const unsigned short* __restrict__ w1fh,
                                                const unsigned short* __restrict__ w1fl,
                                                const unsigned short* __restrict__ w2fh,
                                                const unsigned short* __restrict__ w2fl,
                                                const float* __restrict__ b0,
                                                const float* __restrict__ b1,
                                                const float* __restrict__ b2,
                                                float* __restrict__ y2f) {
    __shared__ unsigned short c1H[32 * K1_S];
    __shared__ unsigned short c1L[32 * K1_S];
    __shared__ unsigned short c2H[32 * K2_S];
    __shared__ unsigned short c2L[32 * K2_S];   // total 26,624 B

    const int b   = blockIdx.y;
    const int n0  = blockIdx.x * 32;
    const int tid = threadIdx.x;
    const int w   = tid >> 6, l = tid & 63;
    const int nt  = w & 1, mh = w >> 1;
    const int lo16 = l & 15, hi = l >> 4;
    const int c = nt * 16 + lo16;          // point column 0..31

    // ---- B-fragments: 32 x 8B loads; dword t of bhs[s] = low dword of load t
    s8v bhs[8], bls[8];
    const unsigned short* fbase = featI + (((size_t)b * 128) * NPAD + (n0 + c)) * 4;
#pragma unroll
    for (int s = 0; s < 8; s++) {
        const int kgb = s * 16 + hi * 4;
        i4v hx, lx;
#pragma unroll
        for (int t = 0; t < 4; t++) {
            int2 v = *(const int2*)(fbase + (size_t)(kgb + t) * (NPAD * 4));
            hx[t] = v.x; lx[t] = v.y;
        }
        bhs[s] = __builtin_bit_cast(s8v, hx);
        bls[s] = __builtin_bit_cast(s8v, lx);
    }

    // ---- layer 0: 128 outs (8 Mt), K=256; wave does Mt = 2mh, 2mh+1 ----
    f4v acc0 = {0.f, 0.f, 0.f, 0.f}, acc1 = {0.f, 0.f, 0.f, 0.f};
#pragma unroll
    for (int s = 0; s < 8; s++) {
        const s8v a0h = mkfrag(w0fh + ((size_t)((mh * 2) * 8 + s) * 64 + l) * 8);
        const s8v a0l = mkfrag(w0fl + ((size_t)((mh * 2) * 8 + s) * 64 + l) * 8);
        const s8v a1h = mkfrag(w0fh + ((size_t)((mh * 2 + 1) * 8 + s) * 64 + l) * 8);
        const s8v a1l = mkfrag(w0fl + ((size_t)((mh * 2 + 1) * 8 + s) * 64 + l) * 8);
        acc0 = __builtin_amdgcn_mfma_f32_16x16x32_bf16(a0h, bhs[s], acc0, 0, 0, 0);
        acc0 = __builtin_amdgcn_mfma_f32_16x16x32_bf16(a0h, bls[s], acc0, 0, 0, 0);
        acc0 = __builtin_amdgcn_mfma_f32_16x16x32_bf16(a0l, bhs[s], acc0, 0, 0, 0);
        acc1 = __builtin_amdgcn_mfma_f32_16x16x32_bf16(a1h, bhs[s], acc1, 0, 0, 0);
        acc1 = __builtin_amdgcn_mfma_f32_16x16x32_bf16(a1h, bls[s], acc1, 0, 0, 0);
        acc1 = __builtin_amdgcn_mfma_f32_16x16x32_bf16(a1l, bhs[s], acc1, 0, 0, 0);
    }
#pragma unroll
    for (int m = 0; m < 2; m++) {
#pragma unroll
        for (int r = 0; r < 4; r++) {
            int ch = (mh * 2 + m) * 16 + hi * 4 + r;
            float v = (m ? acc1[r] : acc0[r]) + b0[ch];
            v = v > 0.f ? v : 0.01f * v;
            unsigned short hh, ll2; bfsplit(v, hh, ll2);
            c1H[c * K1_S + ch] = hh;
            c1L[c * K1_S + ch] = ll2;
        }
    }
    __syncthreads();

    // ---- layer 1: 64 outs (4 Mt), K=128(c1)+256(feat); wave: Mt = mh ----
    f4v accA = {0.f, 0.f, 0.f, 0.f};
#pragma unroll
    for (int s = 0; s < 4; s++) {
        const s8v bh = *(const s8v*)&c1H[c * K1_S + s * 32 + hi * 8];
        const s8v bl = *(const s8v*)&c1L[c * K1_S + s * 32 + hi * 8];
        const s8v ah = mkfrag(w1fh + ((size_t)(mh * 12 + s) * 64 + l) * 8);
        const s8v al = mkfrag(w1fl + ((size_t)(mh * 12 + s) * 64 + l) * 8);
        accA = __builtin_amdgcn_mfma_f32_16x16x32_bf16(ah, bh, accA, 0, 0, 0);
        accA = __builtin_amdgcn_mfma_f32_16x16x32_bf16(ah, bl, accA, 0, 0, 0);
        accA = __builtin_amdgcn_mfma_f32_16x16x32_bf16(al, bh, accA, 0, 0, 0);
    }
#pragma unroll
    for (int s = 4; s < 12; s++) {
        const s8v ah = mkfrag(w1fh + ((size_t)(mh * 12 + s) * 64 + l) * 8);
        const s8v al = mkfrag(w1fl + ((size_t)(mh * 12 + s) * 64 + l) * 8);
        accA = __builtin_amdgcn_mfma_f32_16x16x32_bf16(ah, bhs[s - 4], accA, 0, 0, 0);
        accA = __builtin_amdgcn_mfma_f32_16x16x32_bf16(ah, bls[s - 4], accA, 0, 0, 0);
        accA = __builtin_amdgcn_mfma_f32_16x16x32_bf16(al, bhs[s - 4], accA, 0, 0, 0);
    }
#pragma unroll
    for (int r = 0; r < 4; r++) {
        int ch = mh * 16 + hi * 4 + r;
        float v = accA[r] + b1[ch];
        v = v > 0.f ? v : 0.01f * v;
        unsigned short hh, ll2; bfsplit(v, hh, ll2);
        c2H[c * K2_S + ch] = hh;
        c2L[c * K2_S + ch] = ll2;
    }
    __syncthreads();

    // ---- layer 2: 5 outs (1 Mt), K=64(c2)+256(feat); waves mh==0 ----
    if (mh == 0) {
        f4v acc2 = {0.f, 0.f, 0.f, 0.f};
#pragma unroll
        for (int s = 0; s < 2; s++) {
            const s8v bh = *(const s8v*)&c2H[c * K2_S + s * 32 + hi * 8];
            const s8v bl = *(const s8v*)&c2L[c * K2_S + s * 32 + hi * 8];
            const s8v ah = mkfrag(w2fh + ((size_t)s * 64 + l) * 8);
            const s8v al = mkfrag(w2fl + ((size_t)s * 64 + l) * 8);
            acc2 = __builtin_amdgcn_mfma_f32_16x16x32_bf16(ah, bh, acc2, 0, 0, 0);
            acc2 = __builtin_amdgcn_mfma_f32_16x16x32_bf16(ah, bl, acc2, 0, 0, 0);
            acc2 = __builtin_amdgcn_mfma_f32_16x16x32_bf16(al, bh, acc2, 0, 0, 0);
        }
#pragma unroll
        for (int s = 2; s < 10; s++) {
            const s8v ah = mkfrag(w2fh + ((size_t)s * 64 + l) * 8);
            const s8v al = mkfrag(w2fl + ((size_t)s * 64 + l) * 8);
            acc2 = __builtin_amdgcn_mfma_f32_16x16x32_bf16(ah, bhs[s - 2], acc2, 0, 0, 0);
            acc2 = __builtin_amdgcn_mfma_f32_16x16x32_bf16(ah, bls[s - 2], acc2, 0, 0, 0);
            acc2 = __builtin_amdgcn_mfma_f32_16x16x32_bf16(al, bhs[s - 2], acc2, 0, 0, 0);
        }
#pragma unroll
        for (int r = 0; r < 4; r++) {
            int ch = hi * 4 + r;
            if (ch < 5) {
                float v = acc2[r] + b2[ch];
                v = fmaxf(v, 0.f);
                int n = n0 + c;
                if (n < NN) y2f[(size_t)b * 2500 + ch * NN + n] = v;
            }
        }
    }
}

// ---------------------------------------------------------------------------
// K3: FC two-stage (r11-identical).
// ---------------------------------------------------------------------------
__global__ __launch_bounds__(256) void k_fc1(const float* __restrict__ y2f,
                                             const float* __restrict__ fcwT,
                                             float* __restrict__ part) {
    __shared__ float ys[313];
    const int b  = blockIdx.x & 63;
    const int kc = blockIdx.x >> 6;
    const int start = kc * 312 + (kc < 4 ? kc : 4);
    const int len   = (kc < 4) ? 313 : 312;
    const float* yb = y2f + (size_t)b * 2500 + start;
    for (int j = threadIdx.x; j < len; j += 256) ys[j] = yb[j];
    __syncthreads();
    const int o = threadIdx.x;
    if (o < 236) {
        float acc = 0.f;
        const float* wp = fcwT + (size_t)start * 236 + o;
#pragma unroll 8
        for (int k = 0; k < len; k++) acc = fmaf(wp[(size_t)k * 236], ys[k], acc);
        part[((size_t)kc * 64 + b) * 236 + o] = acc;
    }
}

__global__ __launch_bounds__(256) void k_fc2(const float* __restrict__ part,
                                             const float* __restrict__ fcb,
                                             float* __restrict__ out) {
    const int b = blockIdx.x;
    const int o = threadIdx.x;
    if (o < 236) {
        float acc = fcb[o];
#pragma unroll
        for (int kc = 0; kc < 8; kc++) acc += part[((size_t)kc * 64 + b) * 236 + o];
        out[b * 236 + o] = acc;
    }
}

// ---------------------------------------------------------------------------
extern "C" void kernel_launch(void* const* d_in, const int* in_sizes, int n_in,
                              void* d_out, int out_size, void* d_ws, size_t ws_size,
                              hipStream_t stream) {
    const float* p   = (const float*)d_in[0];
    const float* sf  = (const float*)d_in[1];
    const float* w0  = (const float*)d_in[2];
    const float* b0  = (const float*)d_in[3];
    const float* w1  = (const float*)d_in[4];
    const float* b1  = (const float*)d_in[5];
    const float* w2  = (const float*)d_in[6];
    const float* b2  = (const float*)d_in[7];
    const float* fcw = (const float*)d_in[8];
    const float* fcb = (const float*)d_in[9];
    float* out = (float*)d_out;

    char* ws = (char*)d_ws;
    // ws layout (bytes):
    unsigned short* featI = (unsigned short*)(ws);             // [64][128][512][4] 33,554,432
    float*          y2f   = (float*)(ws + 33554432);           //     640,000
    float*          fcwT  = (float*)(ws + 34194432);           //   2,360,000
    float*          part  = (float*)(ws + 36554432);           //     483,328
    unsigned short* w0fh  = (unsigned short*)(ws + 37037760);  //      65,536
    unsigned short* w0fl  = (unsigned short*)(ws + 37103296);  //      65,536
    unsigned short* w1fh  = (unsigned short*)(ws + 37168832);  //      49,152
    unsigned short* w1fl  = (unsigned short*)(ws + 37217984);  //      49,152
    unsigned short* w2fh  = (unsigned short*)(ws + 37267136);  //      10,240
    unsigned short* w2fl  = (unsigned short*)(ws + 37277376);  //      10,240
                                                               // end: 37,287,616

    k_gp<<<GATHER_BLKS + PACK_BLKS, 512, 0, stream>>>(sf, p, w0, w1, w2, fcw,
                                                      featI, w0fh, w0fl, w1fh, w1fl,
                                                      w2fh, w2fl, fcwT);
    k_mlp<<<dim3(16, BB), 512, 0, stream>>>(featI, w0fh, w0fl, w1fh, w1fl,
                                            w2fh, w2fl, b0, b1, b2, y2f);
    k_fc1<<<512, 256, 0, stream>>>(y2f, fcwT, part);
    k_fc2<<<BB, 256, 0, stream>>>(part, fcb, out);
}

// Round 15
// 82.890 us; speedup vs baseline: 1.5365x; 1.2304x over previous
//
#include <hip/hip_runtime.h>
#include <hip/hip_bf16.h>

// Problem constants
#define BB 64
#define NN 500
#define CC 256
#define HH 64
#define WW 64
#define HWSZ 4096
#define NPTS 32000
#define NPAD 512

typedef __attribute__((ext_vector_type(4))) short s4v;
typedef __attribute__((ext_vector_type(8))) short s8v;
typedef __attribute__((ext_vector_type(4))) float f4v;
typedef __attribute__((ext_vector_type(4))) int i4v;

// RNE round f32 -> bf16 (ushort)
__device__ __forceinline__ unsigned short bfround(float f) {
    unsigned u = __builtin_bit_cast(unsigned, f);
    return (unsigned short)((u + 0x7FFFu + ((u >> 16) & 1u)) >> 16);
}

// ---------------------------------------------------------------------------
// K1: gather (pipelined, r14 skeleton) + weight-pack (plain bf16).
//  blk < 1024: persistent gather block = (batch, 16-channel chunk), 512 thr,
//    2x16KB LDS dbuf, DMA ch t+1 while gathering ch t (vmcnt(2)).
//    Prep once per block. Store paired channels as uint (2xbf16) into
//    featB[b][kg(32)][jp(4)][n(512)] (uint units) — coalesced 4B/lane.
//  blk >= 1024: weight pack: w0f/w1f/w2f bf16 A-fragments with k-labeling
//    row = Mt*16 + (lane&15), k = s*32 + (lane>>4)*8 + j  (r7-verified),
//    + fcwT f32 transpose.
// ---------------------------------------------------------------------------
#define GATHER_BLKS 1024
#define NCHB 16
#define W0F_N 32768   // 8 Mt * 8 s * 512
#define W1F_N 24576   // 4 Mt * 12 s * 512
#define W2F_N 5120    // 1 Mt * 10 s * 512
#define PACK_N (W0F_N + W1F_N + W2F_N)
#define FCT_N 590000
#define PACKALL_N (PACK_N + FCT_N)
#define PACK_BLKS ((PACKALL_N + 511) / 512)

__global__ __launch_bounds__(512) void k_gp(const float* __restrict__ sfeat,
                                            const float* __restrict__ pts,
                                            const float* __restrict__ w0,
                                            const float* __restrict__ w1,
                                            const float* __restrict__ w2,
                                            const float* __restrict__ fcw,
                                            unsigned int* __restrict__ featB,
                                            unsigned short* __restrict__ w0f,
                                            unsigned short* __restrict__ w1f,
                                            unsigned short* __restrict__ w2f,
                                            float* __restrict__ fcwT) {
    __shared__ float im[2][HWSZ];   // 32 KB
    const int blk = blockIdx.x;
    const int tid = threadIdx.x;

    if (blk >= GATHER_BLKS) {
        // ---- pack path ----
        int i = (blk - GATHER_BLKS) * 512 + tid;
        if (i < W0F_N) {
            int j = i & 7, ll = (i >> 3) & 63, s = (i >> 9) & 7, m = i >> 12;
            int row = m * 16 + (ll & 15), k = s * 32 + (ll >> 4) * 8 + j;
            w0f[i] = bfround(w0[row * 256 + k]);
        } else if (i < W0F_N + W1F_N) {
            int d = i - W0F_N;
            int j = d & 7, ll = (d >> 3) & 63, rest = d >> 9;
            int s = rest % 12, m = rest / 12;
            int row = m * 16 + (ll & 15), k = s * 32 + (ll >> 4) * 8 + j;
            w1f[d] = bfround(w1[row * 384 + k]);
        } else if (i < PACK_N) {
            int d = i - (W0F_N + W1F_N);
            int j = d & 7, ll = (d >> 3) & 63, s = d >> 9;
            int row = ll & 15, k = s * 32 + (ll >> 4) * 8 + j;
            float v = (row < 5) ? w2[row * 320 + k] : 0.f;
            w2f[d] = bfround(v);
        } else if (i < PACKALL_N) {
            int d = i - PACK_N;
            int k = d / 236, o = d - k * 236;
            fcwT[d] = fcw[o * 2500 + k];
        }
        return;
    }

    // ---- gather path ----
    const int b     = blk >> 4;
    const int chunk = blk & 15;
    const int ch0   = chunk * NCHB;
    const int n     = tid;

    // per-point bilinear prep, once per block
    int4 id = make_int4(0, 0, 0, 0);
    float4 wt = make_float4(0.f, 0.f, 0.f, 0.f);
    if (n < NN) {
        float x = (pts[((size_t)b * NN + n) * 2 + 0] + 1.f) * 0.5f * (float)(WW - 1);
        float y = (pts[((size_t)b * NN + n) * 2 + 1] + 1.f) * 0.5f * (float)(HH - 1);
        float x0f = floorf(x), y0f = floorf(y);
        float x1f = x0f + 1.f, y1f = y0f + 1.f;
        float wx1 = x - x0f, wx0 = 1.f - wx1;
        float wy1 = y - y0f, wy0 = 1.f - wy1;
        float mx0 = (x0f >= 0.f && x0f <= (float)(WW - 1)) ? 1.f : 0.f;
        float mx1 = (x1f >= 0.f && x1f <= (float)(WW - 1)) ? 1.f : 0.f;
        float my0 = (y0f >= 0.f && y0f <= (float)(HH - 1)) ? 1.f : 0.f;
        float my1 = (y1f >= 0.f && y1f <= (float)(HH - 1)) ? 1.f : 0.f;
        int x0 = (int)fminf(fmaxf(x0f, 0.f), (float)(WW - 1));
        int x1 = (int)fminf(fmaxf(x1f, 0.f), (float)(WW - 1));
        int y0 = (int)fminf(fmaxf(y0f, 0.f), (float)(HH - 1));
        int y1 = (int)fminf(fmaxf(y1f, 0.f), (float)(HH - 1));
        id = make_int4(y0 * WW + x0, y0 * WW + x1, y1 * WW + x0, y1 * WW + x1);
        wt = make_float4(wx0 * wy0 * mx0 * my0, wx1 * wy0 * mx1 * my0,
                         wx0 * wy1 * mx0 * my1, wx1 * wy1 * mx1 * my1);
    }

    const float4* src = (const float4*)(sfeat + ((size_t)b * CC + ch0) * HWSZ);

    // prologue: DMA ch 0 -> buf 0
#pragma unroll
    for (int it = 0; it < 2; it++) {
        int j = it * 512 + tid;
        __builtin_amdgcn_global_load_lds(
            (const __attribute__((address_space(1))) void*)(src + j),
            (__attribute__((address_space(3))) void*)((float4*)im[0] + j),
            16, 0, 0);
    }

    unsigned short hprev = 0;
    for (int t = 0; t < NCHB; t++) {
        if (t + 1 < NCHB) {
            const float4* s2 = src + (size_t)(t + 1) * (HWSZ / 4);
            float4* dst = (float4*)im[(t + 1) & 1];
#pragma unroll
            for (int it = 0; it < 2; it++) {
                int j = it * 512 + tid;
                __builtin_amdgcn_global_load_lds(
                    (const __attribute__((address_space(1))) void*)(s2 + j),
                    (__attribute__((address_space(3))) void*)(dst + j),
                    16, 0, 0);
            }
            asm volatile("s_waitcnt vmcnt(2)" ::: "memory");  // ch t landed
        } else {
            asm volatile("s_waitcnt vmcnt(0)" ::: "memory");
        }
        asm volatile("s_barrier" ::: "memory");

        if (n < NN) {
            const float* L = im[t & 1];
            float r = wt.x * L[id.x] + wt.y * L[id.y] + wt.z * L[id.z] + wt.w * L[id.w];
            unsigned short h = bfround(r);
            if (t & 1) {
                unsigned int v = (unsigned int)hprev | ((unsigned int)h << 16);
                int kg = chunk * 2 + (t >> 3);
                int jp = (t & 7) >> 1;
                featB[(((size_t)b * 32 + kg) * 4 + jp) * 512 + n] = v;
            } else {
                hprev = h;
            }
        }
        if (t + 1 < NCHB)
            asm volatile("s_barrier" ::: "memory");
    }
}

// ---------------------------------------------------------------------------
// K2: plain-bf16 MFMA fused MLP. Structure as r11 but single array per
// operand, 1 MFMA per (Mt,s). Wave w: nt=w&1, mh=w>>1.
// k-labeling k = s*32 + (l>>4)*8 + j identical on A and B sides.
// C/D mapping (m89-verified): col = lane&15, row = (lane>>4)*4 + reg.
// ---------------------------------------------------------------------------
#define K1_S 136
#define K2_S 72

__device__ __forceinline__ s8v mkfrag(const unsigned short* p) {
    return *(const s8v*)p;
}

__global__ __launch_bounds__(512, 4) void k_mlp(const unsigned int* __restrict__ featB,
                                                const unsigned short* __restrict__ w0f,
                                                const unsigned short* __restrict__ w1f,
                                                const unsigned short* __restrict__ w2f,
                                                const float* __restrict__ b0,
                                                const float* __restrict__ b1,
                                                const float* __restrict__ b2,
                                                float* __restrict__ y2f) {
    __shared__ unsigned short c1B[32 * K1_S];
    __shared__ unsigned short c2B[32 * K2_S];   // total 13,312 B

    const int b   = blockIdx.y;
    const int n0  = blockIdx.x * 32;
    const int tid = threadIdx.x;
    const int w   = tid >> 6, l = tid & 63;
    const int nt  = w & 1, mh = w >> 1;
    const int lo16 = l & 15, hi = l >> 4;
    const int c = nt * 16 + lo16;          // point column 0..31

    // ---- B-fragments: 32 x 4B coalesced loads ----
    s8v bhs[8];
    const unsigned int* fb = featB + (size_t)b * (32 * 4 * 512) + (n0 + c);
#pragma unroll
    for (int s = 0; s < 8; s++) {
        const int kg = s * 4 + hi;
        i4v hx;
#pragma unroll
        for (int t = 0; t < 4; t++)
            hx[t] = (int)fb[(size_t)(kg * 4 + t) * 512];
        bhs[s] = __builtin_bit_cast(s8v, hx);
    }

    // ---- layer 0: 128 outs (8 Mt), K=256; wave does Mt = 2mh, 2mh+1 ----
    f4v acc0 = {0.f, 0.f, 0.f, 0.f}, acc1 = {0.f, 0.f, 0.f, 0.f};
#pragma unroll
    for (int s = 0; s < 8; s++) {
        const s8v a0 = mkfrag(w0f + ((size_t)((mh * 2) * 8 + s) * 64 + l) * 8);
        const s8v a1 = mkfrag(w0f + ((size_t)((mh * 2 + 1) * 8 + s) * 64 + l) * 8);
        acc0 = __builtin_amdgcn_mfma_f32_16x16x32_bf16(a0, bhs[s], acc0, 0, 0, 0);
        acc1 = __builtin_amdgcn_mfma_f32_16x16x32_bf16(a1, bhs[s], acc1, 0, 0, 0);
    }
#pragma unroll
    for (int m = 0; m < 2; m++) {
#pragma unroll
        for (int r = 0; r < 4; r++) {
            int ch = (mh * 2 + m) * 16 + hi * 4 + r;
            float v = (m ? acc1[r] : acc0[r]) + b0[ch];
            v = v > 0.f ? v : 0.01f * v;
            c1B[c * K1_S + ch] = bfround(v);
        }
    }
    __syncthreads();

    // ---- layer 1: 64 outs (4 Mt), K=128(c1)+256(feat); wave: Mt = mh ----
    f4v accA = {0.f, 0.f, 0.f, 0.f};
#pragma unroll
    for (int s = 0; s < 4; s++) {
        const s8v bh = *(const s8v*)&c1B[c * K1_S + s * 32 + hi * 8];
        const s8v a  = mkfrag(w1f + ((size_t)(mh * 12 + s) * 64 + l) * 8);
        accA = __builtin_amdgcn_mfma_f32_16x16x32_bf16(a, bh, accA, 0, 0, 0);
    }
#pragma unroll
    for (int s = 4; s < 12; s++) {
        const s8v a = mkfrag(w1f + ((size_t)(mh * 12 + s) * 64 + l) * 8);
        accA = __builtin_amdgcn_mfma_f32_16x16x32_bf16(a, bhs[s - 4], accA, 0, 0, 0);
    }
#pragma unroll
    for (int r = 0; r < 4; r++) {
        int ch = mh * 16 + hi * 4 + r;
        float v = accA[r] + b1[ch];
        v = v > 0.f ? v : 0.01f * v;
        c2B[c * K2_S + ch] = bfround(v);
    }
    __syncthreads();

    // ---- layer 2: 5 outs (1 Mt), K=64(c2)+256(feat); waves mh==0 ----
    if (mh == 0) {
        f4v acc2 = {0.f, 0.f, 0.f, 0.f};
#pragma unroll
        for (int s = 0; s < 2; s++) {
            const s8v bh = *(const s8v*)&c2B[c * K2_S + s * 32 + hi * 8];
            const s8v a  = mkfrag(w2f + ((size_t)s * 64 + l) * 8);
            acc2 = __builtin_amdgcn_mfma_f32_16x16x32_bf16(a, bh, acc2, 0, 0, 0);
        }
#pragma unroll
        for (int s = 2; s < 10; s++) {
            const s8v a = mkfrag(w2f + ((size_t)s * 64 + l) * 8);
            acc2 = __builtin_amdgcn_mfma_f32_16x16x32_bf16(a, bhs[s - 2], acc2, 0, 0, 0);
        }
#pragma unroll
        for (int r = 0; r < 4; r++) {
            int ch = hi * 4 + r;
            if (ch < 5) {
                float v = acc2[r] + b2[ch];
                v = fmaxf(v, 0.f);
                int n = n0 + c;
                if (n < NN) y2f[(size_t)b * 2500 + ch * NN + n] = v;
            }
        }
    }
}

// ---------------------------------------------------------------------------
// K3: FC two-stage (r11-identical).
// ---------------------------------------------------------------------------
__global__ __launch_bounds__(256) void k_fc1(const float* __restrict__ y2f,
                                             const float* __restrict__ fcwT,
                                             float* __restrict__ part) {
    __shared__ float ys[313];
    const int b  = blockIdx.x & 63;
    const int kc = blockIdx.x >> 6;
    const int start = kc * 312 + (kc < 4 ? kc : 4);
    const int len   = (kc < 4) ? 313 : 312;
    const float* yb = y2f + (size_t)b * 2500 + start;
    for (int j = threadIdx.x; j < len; j += 256) ys[j] = yb[j];
    __syncthreads();
    const int o = threadIdx.x;
    if (o < 236) {
        float acc = 0.f;
        const float* wp = fcwT + (size_t)start * 236 + o;
#pragma unroll 8
        for (int k = 0; k < len; k++) acc = fmaf(wp[(size_t)k * 236], ys[k], acc);
        part[((size_t)kc * 64 + b) * 236 + o] = acc;
    }
}

__global__ __launch_bounds__(256) void k_fc2(const float* __restrict__ part,
                                             const float* __restrict__ fcb,
                                             float* __restrict__ out) {
    const int b = blockIdx.x;
    const int o = threadIdx.x;
    if (o < 236) {
        float acc = fcb[o];
#pragma unroll
        for (int kc = 0; kc < 8; kc++) acc += part[((size_t)kc * 64 + b) * 236 + o];
        out[b * 236 + o] = acc;
    }
}

// ---------------------------------------------------------------------------
extern "C" void kernel_launch(void* const* d_in, const int* in_sizes, int n_in,
                              void* d_out, int out_size, void* d_ws, size_t ws_size,
                              hipStream_t stream) {
    const float* p   = (const float*)d_in[0];
    const float* sf  = (const float*)d_in[1];
    const float* w0  = (const float*)d_in[2];
    const float* b0  = (const float*)d_in[3];
    const float* w1  = (const float*)d_in[4];
    const float* b1  = (const float*)d_in[5];
    const float* w2  = (const float*)d_in[6];
    const float* b2  = (const float*)d_in[7];
    const float* fcw = (const float*)d_in[8];
    const float* fcb = (const float*)d_in[9];
    float* out = (float*)d_out;

    char* ws = (char*)d_ws;
    // ws layout (bytes):
    unsigned int*   featB = (unsigned int*)(ws);               // [64][32][4][512] u32 16,777,216
    float*          y2f   = (float*)(ws + 16777216);           //     640,000
    float*          fcwT  = (float*)(ws + 17417216);           //   2,360,000
    float*          part  = (float*)(ws + 19777216);           //     483,328
    unsigned short* w0f   = (unsigned short*)(ws + 20260544);  //      65,536
    unsigned short* w1f   = (unsigned short*)(ws + 20326080);  //      49,152
    unsigned short* w2f   = (unsigned short*)(ws + 20375232);  //      10,240
                                                               // end: 20,385,472

    k_gp<<<GATHER_BLKS + PACK_BLKS, 512, 0, stream>>>(sf, p, w0, w1, w2, fcw,
                                                      featB, w0f, w1f, w2f, fcwT);
    k_mlp<<<dim3(16, BB), 512, 0, stream>>>(featB, w0f, w1f, w2f,
                                            b0, b1, b2, y2f);
    k_fc1<<<512, 256, 0, stream>>>(y2f, fcwT, part);
    k_fc2<<<BB, 256, 0, stream>>>(part, fcb, out);
}